// Round 11
// baseline (3698.881 us; speedup 1.0000x reference)
//
#include <hip/hip_runtime.h>
#include <hip/hip_bf16.h>

// ============================================================================
// PPO agent fused forward (round 11):
//  r1-r10 verdict: the fully-fused 6-layer kernel's live state (~150-250 regs)
//  never fits an occupancy box -> pinned at 2 waves/SIMD or scratch-spilling.
//  New structure: per-layer kernels + chunked global activation handoff.
//   - l1_kernel: the three K=64 layers (actor(s), critic(s), critic(ns)),
//     one X load pair; writes h1 bufs in k-permuted row layout (bf16).
//   - actor23_kernel: L2+LN (+L3+softmax) -> out cols 0..17.
//   - critic23_kernel (grid.y=2): L2+LN+L3 -> vbuf / nvbuf.
//   - gae_kernel: deltas computed inline from (rewards,masks,vbuf,nvbuf),
//     wave-parallel affine scan -> out cols 18,19.
//   - T chunked (C=65536 rows, ws-size adaptive): 3 act bufs = 100MB, stays
//     L3-resident -> HBM traffic ~0.5GB.
//  Each kernel ~80-110 regs; __launch_bounds__(256,4) -> 4+ waves/SIMD.
//  Numerics identical to r8/r10 (same rounding points). absmax ~0.125-0.25.
// ============================================================================

#define T_SZ 524288
#define GL 0.9405f   // GAMMA*LAM

typedef __attribute__((ext_vector_type(8))) short bf16x8;   // 8 bf16 (4 VGPRs)
typedef __attribute__((ext_vector_type(4))) float f32x4;

// ws layout: weights (bf16, k-permuted [N][K]) | vbuf f32[T] | nvbuf f32[T] | h1 bufs
#define OFF_AW1T 0        // [256][64]
#define OFF_AW2T 16384    // [256][256]
#define OFF_AW3T 81920    // [32][256]  rows >=18 zero
#define OFF_CW1T 90112    // [256][64]
#define OFF_CW2T 106496   // [256][256]
#define OFF_CW3T 172032   // [16][256]  rows >=1 zero
#define W_ELEMS  176128
#define OFF_V_BYTES   352256
#define OFF_NV_BYTES  2449408
#define OFF_H1_BYTES  4546560

// k = p*32 + h*16 + w (w=k&15, h=(k>>4)&1) -> pos = p*32 + w*2 + h
// Applied to activations AND weights -> MFMA k-sum invariant.
__device__ __forceinline__ int perm_k(int k) {
  return (k & ~31) | ((k & 15) << 1) | ((k >> 4) & 1);
}

__device__ __forceinline__ unsigned pack2(float a, float b) {
  union { __hip_bfloat16 h; unsigned short u; } ua, ub;
  ua.h = __float2bfloat16(a); ub.h = __float2bfloat16(b);
  return (unsigned)ua.u | ((unsigned)ub.u << 16);
}

__device__ __forceinline__ void unpack2(unsigned u, float& a, float& b) {
  union { unsigned u; float f; } x, y;
  x.u = u << 16; y.u = u & 0xFFFF0000u;
  a = x.f; b = y.f;
}

// per-wave LDS stash accessor (stride 512B, 16B-granular XOR on row&7)
__device__ __forceinline__ void* act_at(void* base, int row, int colByte) {
  return (char*)base + row * 512 + (colByte ^ ((row & 7) << 4));
}

// ---------------------------------------------------------------------------
// X tile (16 rows x 64 fp32) -> 2 k-permuted bf16x8 frags per lane.
__device__ __forceinline__ void load_x_frags(const float* __restrict__ src,
                                             int c, int q, bf16x8* xf) {
  const float* rp = src + (size_t)c * 64;
#pragma unroll
  for (int ks = 0; ks < 2; ++ks) {
    float4 a = *(const float4*)(rp + ks * 32 + 4 * q);
    float4 b = *(const float4*)(rp + ks * 32 + 4 * q + 16);
    unsigned u[4];
    u[0] = pack2(a.x, b.x); u[1] = pack2(a.y, b.y);
    u[2] = pack2(a.z, b.z); u[3] = pack2(a.w, b.w);
    xf[ks] = *(bf16x8*)u;
  }
}

// h1 row (k-perm layout) -> 8 frags, direct b128 loads
__device__ __forceinline__ void load_h1_frags(const __hip_bfloat16* __restrict__ h1,
                                              int lrow, int c, int q, bf16x8* af) {
  const char* rp = (const char*)(h1 + (size_t)(lrow + c) * 256);
#pragma unroll
  for (int ks = 0; ks < 8; ++ks)
    af[ks] = *(const bf16x8*)(rp + ks * 64 + q * 16);
}

// ---------------------------------------------------------------------------
// shared LN tail: reduce s/ss, broadcast row-c stats -> (mc, rc)
__device__ __forceinline__ void ln_stats(float* s, float* ss, int c,
                                         float& mc, float& rc) {
#pragma unroll
  for (int m = 1; m < 16; m <<= 1) {
#pragma unroll
    for (int r = 0; r < 4; ++r) {
      s[r]  += __shfl_xor(s[r],  m, 64);
      ss[r] += __shfl_xor(ss[r], m, 64);
    }
  }
  float mean[4], rs[4];
#pragma unroll
  for (int r = 0; r < 4; ++r) {
    mean[r] = s[r] * (1.f / 256.f);
    float var = ss[r] * (1.f / 256.f) - mean[r] * mean[r];
    rs[r] = rsqrtf(var + 1e-5f);
  }
  const int srcLane = ((c >> 2) << 4) + c;   // row c's stats: lane q'=c>>2, slot c&3
  float mb[4], rb[4];
#pragma unroll
  for (int r = 0; r < 4; ++r) {
    mb[r] = __shfl(mean[r], srcLane, 64);
    rb[r] = __shfl(rs[r],   srcLane, 64);
  }
  const float m01 = (c & 1) ? mb[1] : mb[0], m23 = (c & 1) ? mb[3] : mb[2];
  const float r01 = (c & 1) ? rb[1] : rb[0], r23 = (c & 1) ? rb[3] : rb[2];
  mc = (c & 2) ? m23 : m01;
  rc = (c & 2) ? r23 : r01;
}

// ---------------------------------------------------------------------------
// L1: Linear(64->256)+LN+ReLU, result to global h1 (k-perm row layout).
__device__ __forceinline__ void l1_one(const bf16x8* xf,
    const __hip_bfloat16* __restrict__ Wt,
    const float* __restrict__ bias, const float* __restrict__ gam,
    const float* __restrict__ bet, void* ACT,
    __hip_bfloat16* __restrict__ h1, int lrow, int c, int q) {
  float s[4] = {0, 0, 0, 0}, ss[4] = {0, 0, 0, 0};
#pragma unroll
  for (int p = 0; p < 8; ++p) {
    f32x4 a0 = {0.f, 0.f, 0.f, 0.f}, a1 = {0.f, 0.f, 0.f, 0.f};
    const __hip_bfloat16* wp = Wt + (size_t)(32 * p + c) * 64 + q * 8;
#pragma unroll
    for (int ks = 0; ks < 2; ++ks) {
      bf16x8 b0 = *(const bf16x8*)(wp + ks * 32);
      bf16x8 b1 = *(const bf16x8*)(wp + 16 * 64 + ks * 32);
      a0 = __builtin_amdgcn_mfma_f32_16x16x32_bf16(xf[ks], b0, a0, 0, 0, 0);
      a1 = __builtin_amdgcn_mfma_f32_16x16x32_bf16(xf[ks], b1, a1, 0, 0, 0);
    }
    const float bb0 = bias[32 * p + c], bb1 = bias[32 * p + 16 + c];
#pragma unroll
    for (int r = 0; r < 4; ++r) {
      float v0 = a0[r] + bb0, v1 = a1[r] + bb1;
      s[r] += v0 + v1;
      ss[r] += v0 * v0 + v1 * v1;
      *(unsigned*)act_at(ACT, q * 4 + r, p * 64 + c * 4) = pack2(v0, v1);
    }
  }
  float mc, rc;
  ln_stats(s, ss, c, mc, rc);
  char* orow = (char*)(h1 + (size_t)(lrow + c) * 256);
#pragma unroll
  for (int ks = 0; ks < 8; ++ks) {
    uint4 dv = *(const uint4*)act_at(ACT, c, ks * 64 + q * 16);
    unsigned w[4];
    const unsigned* dp = (const unsigned*)&dv;
#pragma unroll
    for (int i = 0; i < 4; ++i) {
      const int n0 = ks * 32 + q * 4 + i;
      float v0, v1;
      unpack2(dp[i], v0, v1);
      float w0 = fmaxf((v0 - mc) * rc * gam[n0]      + bet[n0],      0.f);
      float w1 = fmaxf((v1 - mc) * rc * gam[n0 + 16] + bet[n0 + 16], 0.f);
      w[i] = pack2(w0, w1);
    }
    *(uint4*)(orow + ks * 64 + q * 16) = *(uint4*)w;
  }
}

// ---------------------------------------------------------------------------
// L2: Linear(256->256)+LN+ReLU, A-frags in regs, B streamed; frags out.
__device__ __forceinline__ void layer256_ln(const bf16x8* af,
    const __hip_bfloat16* __restrict__ Wt,
    const float* __restrict__ bias, const float* __restrict__ gam,
    const float* __restrict__ bet, void* ACT, int c, int q, bf16x8* of) {
  float s[4] = {0, 0, 0, 0}, ss[4] = {0, 0, 0, 0};
#pragma unroll
  for (int p = 0; p < 8; ++p) {
    f32x4 a0 = {0.f, 0.f, 0.f, 0.f}, a1 = {0.f, 0.f, 0.f, 0.f};
    const __hip_bfloat16* wp = Wt + (size_t)(32 * p + c) * 256 + q * 8;
#pragma unroll
    for (int ks = 0; ks < 8; ++ks) {
      bf16x8 b0 = *(const bf16x8*)(wp + ks * 32);
      bf16x8 b1 = *(const bf16x8*)(wp + 16 * 256 + ks * 32);
      a0 = __builtin_amdgcn_mfma_f32_16x16x32_bf16(af[ks], b0, a0, 0, 0, 0);
      a1 = __builtin_amdgcn_mfma_f32_16x16x32_bf16(af[ks], b1, a1, 0, 0, 0);
    }
    const float bb0 = bias[32 * p + c], bb1 = bias[32 * p + 16 + c];
#pragma unroll
    for (int r = 0; r < 4; ++r) {
      float v0 = a0[r] + bb0, v1 = a1[r] + bb1;
      s[r] += v0 + v1;
      ss[r] += v0 * v0 + v1 * v1;
      *(unsigned*)act_at(ACT, q * 4 + r, p * 64 + c * 4) = pack2(v0, v1);
    }
  }
  float mc, rc;
  ln_stats(s, ss, c, mc, rc);
#pragma unroll
  for (int ks = 0; ks < 8; ++ks) {
    uint4 dv = *(const uint4*)act_at(ACT, c, ks * 64 + q * 16);
    unsigned w[4];
    const unsigned* dp = (const unsigned*)&dv;
#pragma unroll
    for (int i = 0; i < 4; ++i) {
      const int n0 = ks * 32 + q * 4 + i;
      float v0, v1;
      unpack2(dp[i], v0, v1);
      float w0 = fmaxf((v0 - mc) * rc * gam[n0]      + bet[n0],      0.f);
      float w1 = fmaxf((v1 - mc) * rc * gam[n0 + 16] + bet[n0 + 16], 0.f);
      w[i] = pack2(w0, w1);
    }
    of[ks] = *(bf16x8*)w;
  }
}

// small final GEMM (no LN): NT column-tiles of 16, K=256
template<int NT>
__device__ __forceinline__ void run_small(const bf16x8* af,
    const __hip_bfloat16* __restrict__ Wt, int c, int q, f32x4* acc) {
#pragma unroll
  for (int nt = 0; nt < NT; ++nt) acc[nt] = (f32x4){0.f, 0.f, 0.f, 0.f};
#pragma unroll
  for (int ks = 0; ks < 8; ++ks) {
#pragma unroll
    for (int nt = 0; nt < NT; ++nt) {
      bf16x8 b = *(const bf16x8*)(Wt + (size_t)(nt * 16 + c) * 256 + ks * 32 + q * 8);
      acc[nt] = __builtin_amdgcn_mfma_f32_16x16x32_bf16(af[ks], b, acc[nt], 0, 0, 0);
    }
  }
}

__device__ __forceinline__ void softmax_write(f32x4* acc3,
    const float* __restrict__ ab3, float* __restrict__ out,
    int grow0, int c, int q) {
  float b0 = ab3[c];
  float b1 = (c < 2) ? ab3[16 + c] : 0.f;
#pragma unroll
  for (int r = 0; r < 4; ++r) {
    float x0 = acc3[0][r] + b0;
    float x1 = (c < 2) ? (acc3[1][r] + b1) : -1e30f;
    float mx = fmaxf(x0, x1);
#pragma unroll
    for (int m = 1; m < 16; m <<= 1) mx = fmaxf(mx, __shfl_xor(mx, m, 64));
    float e0 = __expf(x0 - mx);
    float e1 = (c < 2) ? __expf(x1 - mx) : 0.f;
    float sm = e0 + e1;
#pragma unroll
    for (int m = 1; m < 16; m <<= 1) sm += __shfl_xor(sm, m, 64);
    float inv = 1.f / sm;
    int gr = grow0 + q * 4 + r;
    out[(size_t)gr * 20 + c] = e0 * inv;
    if (c < 2) out[(size_t)gr * 20 + 16 + c] = e1 * inv;
  }
}

// ---------------------------------------------------------------------------
__global__ void prep_weights(const float* __restrict__ aw1, const float* __restrict__ aw2,
                             const float* __restrict__ aw3, const float* __restrict__ cw1,
                             const float* __restrict__ cw2, const float* __restrict__ cw3,
                             __hip_bfloat16* __restrict__ wb) {
  int i = blockIdx.x * 256 + threadIdx.x;
  if (i >= W_ELEMS) return;
  float v; int dst;
  if (i < OFF_AW2T)      { int j = i;            int n = j >> 6, k = j & 63;  v = aw1[k * 256 + n];              dst = OFF_AW1T + n * 64  + perm_k(k); }
  else if (i < OFF_AW3T) { int j = i - OFF_AW2T; int n = j >> 8, k = j & 255; v = aw2[k * 256 + n];              dst = OFF_AW2T + n * 256 + perm_k(k); }
  else if (i < OFF_CW1T) { int j = i - OFF_AW3T; int n = j >> 8, k = j & 255; v = (n < 18) ? aw3[k * 18 + n] : 0.f; dst = OFF_AW3T + n * 256 + perm_k(k); }
  else if (i < OFF_CW2T) { int j = i - OFF_CW1T; int n = j >> 6, k = j & 63;  v = cw1[k * 256 + n];              dst = OFF_CW1T + n * 64  + perm_k(k); }
  else if (i < OFF_CW3T) { int j = i - OFF_CW2T; int n = j >> 8, k = j & 255; v = cw2[k * 256 + n];              dst = OFF_CW2T + n * 256 + perm_k(k); }
  else                   { int j = i - OFF_CW3T; int n = j >> 8, k = j & 255; v = (n == 0) ? cw3[k] : 0.f;       dst = OFF_CW3T + n * 256 + perm_k(k); }
  wb[dst] = __float2bfloat16(v);
}

// ---------------------------------------------------------------------------
// L1 kernel: three K=64 layers; one X load pair per wave.
__global__ __launch_bounds__(256, 4) void l1_kernel(
    const float* __restrict__ states, const float* __restrict__ next_states,
    const float* __restrict__ ab1, const float* __restrict__ ag1, const float* __restrict__ an1,
    const float* __restrict__ cb1, const float* __restrict__ cg1, const float* __restrict__ cn1,
    const __hip_bfloat16* __restrict__ wbuf,
    __hip_bfloat16* __restrict__ h1a, __hip_bfloat16* __restrict__ h1cs,
    __hip_bfloat16* __restrict__ h1cn, int chunk_base) {
  __shared__ char ACTb[4][8192];
  const int tid = threadIdx.x;
  const int wave = tid >> 6, lane = tid & 63;
  const int c = lane & 15, q = lane >> 4;
  void* ACT = (void*)ACTb[wave];
  const int lrow = blockIdx.x * 64 + wave * 16;
  const int grow = chunk_base + lrow;

  bf16x8 xs[2], xn[2];
  load_x_frags(states + (size_t)grow * 64, c, q, xs);
  load_x_frags(next_states + (size_t)grow * 64, c, q, xn);

  l1_one(xs, wbuf + OFF_AW1T, ab1, ag1, an1, ACT, h1a, lrow, c, q);
  l1_one(xs, wbuf + OFF_CW1T, cb1, cg1, cn1, ACT, h1cs, lrow, c, q);
  l1_one(xn, wbuf + OFF_CW1T, cb1, cg1, cn1, ACT, h1cn, lrow, c, q);
}

// ---------------------------------------------------------------------------
// Actor L2+L3: h1a -> h2 -> logits -> softmax -> out cols 0..17
__global__ __launch_bounds__(256, 4) void actor23_kernel(
    const __hip_bfloat16* __restrict__ h1a,
    const float* __restrict__ ab2, const float* __restrict__ ag2, const float* __restrict__ an2,
    const float* __restrict__ ab3,
    const __hip_bfloat16* __restrict__ wbuf,
    float* __restrict__ out, int chunk_base) {
  __shared__ char ACTb[4][8192];
  const int tid = threadIdx.x;
  const int wave = tid >> 6, lane = tid & 63;
  const int c = lane & 15, q = lane >> 4;
  void* ACT = (void*)ACTb[wave];
  const int lrow = blockIdx.x * 64 + wave * 16;

  bf16x8 af[8];
  load_h1_frags(h1a, lrow, c, q, af);
  layer256_ln(af, wbuf + OFF_AW2T, ab2, ag2, an2, ACT, c, q, af);
  f32x4 p3[2];
  run_small<2>(af, wbuf + OFF_AW3T, c, q, p3);
  softmax_write(p3, ab3, out, chunk_base + lrow, c, q);
}

// ---------------------------------------------------------------------------
// Critic L2+L3 (grid.y: 0=states->vbuf, 1=next_states->nvbuf)
__global__ __launch_bounds__(256, 4) void critic23_kernel(
    const __hip_bfloat16* __restrict__ h1cs, const __hip_bfloat16* __restrict__ h1cn,
    const float* __restrict__ cb2, const float* __restrict__ cg2, const float* __restrict__ cn2,
    const float* __restrict__ cb3,
    const __hip_bfloat16* __restrict__ wbuf,
    float* __restrict__ vbuf, float* __restrict__ nvbuf, int chunk_base) {
  __shared__ char ACTb[4][8192];
  const int tid = threadIdx.x;
  const int wave = tid >> 6, lane = tid & 63;
  const int c = lane & 15, q = lane >> 4;
  void* ACT = (void*)ACTb[wave];
  const int lrow = blockIdx.x * 64 + wave * 16;
  const __hip_bfloat16* h1 = blockIdx.y ? h1cn : h1cs;
  float* vo = blockIdx.y ? nvbuf : vbuf;

  bf16x8 af[8];
  load_h1_frags(h1, lrow, c, q, af);
  layer256_ln(af, wbuf + OFF_CW2T, cb2, cg2, cn2, ACT, c, q, af);
  f32x4 v[1];
  run_small<1>(af, wbuf + OFF_CW3T, c, q, v);
  const float b3 = cb3[0];
  if (c == 0) {
#pragma unroll
    for (int r = 0; r < 4; ++r)
      vo[chunk_base + lrow + q * 4 + r] = v[0][r] + b3;
  }
}

// ---------------------------------------------------------------------------
// GAE: deltas inline from (rewards, masks, vbuf, nvbuf); wave-parallel affine
// suffix scan, 512-elem lookahead (GL^512 ~ 2e-14). Writes out cols 18,19.
__global__ __launch_bounds__(256) void gae_kernel(
    const float* __restrict__ rewards, const float* __restrict__ masks,
    const float* __restrict__ vbuf, const float* __restrict__ nvbuf,
    float* __restrict__ out) {
  const int w = (blockIdx.x * blockDim.x + threadIdx.x) >> 6;  // 0..1023
  const int lane = threadIdx.x & 63;
  const int idx0 = w * 512 + lane * 16;

  float d[16], cf[16], vv[16];
  if (idx0 < T_SZ) {
#pragma unroll
    for (int i = 0; i < 4; ++i) {
      float4 rw = *(const float4*)(rewards + idx0 + i * 4);
      float4 mk = *(const float4*)(masks + idx0 + i * 4);
      float4 va = *(const float4*)(vbuf + idx0 + i * 4);
      float4 nv = *(const float4*)(nvbuf + idx0 + i * 4);
      const float* rwp = &rw.x; const float* mkp = &mk.x;
      const float* vap = &va.x; const float* nvp = &nv.x;
#pragma unroll
      for (int j = 0; j < 4; ++j) {
        const int i4 = i * 4 + j;
        vv[i4] = vap[j];
        d[i4] = rwp[j] + 0.99f * nvp[j] * mkp[j] - vap[j];
        cf[i4] = GL * mkp[j];
      }
    }
  } else {
#pragma unroll
    for (int i = 0; i < 16; ++i) { d[i] = 0.f; cf[i] = 0.f; vv[i] = 0.f; }
  }

  // local affine: this block maps incoming g -> A + P*g
  float A = 0.f, P = 1.f;
#pragma unroll
  for (int i = 15; i >= 0; --i) { A = d[i] + cf[i] * A; P *= cf[i]; }

  // suffix-inclusive scan over lanes
  float As = A, Ps = P;
#pragma unroll
  for (int st = 1; st < 64; st <<= 1) {
    float An = __shfl_down(As, st, 64);
    float Pn = __shfl_down(Ps, st, 64);
    if (lane + st < 64) { As = As + Ps * An; Ps = Ps * Pn; }
  }
  float G = __shfl_down(As, 1, 64);   // exclusive carry from lanes l+1..63
  if (lane == 63) G = 0.f;

  if (lane < 32) {                    // first 512 elems are this wave's output
    float g = G;
#pragma unroll
    for (int i = 15; i >= 0; --i) {
      g = d[i] + cf[i] * g;
      const size_t j = (size_t)(idx0 + i);
      out[j * 20 + 18] = g;
      out[j * 20 + 19] = g + vv[i];
    }
  }
}

// ---------------------------------------------------------------------------
extern "C" void kernel_launch(void* const* d_in, const int* in_sizes, int n_in,
                              void* d_out, int out_size, void* d_ws, size_t ws_size,
                              hipStream_t stream) {
  const float* states      = (const float*)d_in[0];
  const float* next_states = (const float*)d_in[1];
  const float* rewards     = (const float*)d_in[2];
  const float* masks       = (const float*)d_in[3];
  const float* aw1 = (const float*)d_in[4];
  const float* ab1 = (const float*)d_in[5];
  const float* ag1 = (const float*)d_in[6];
  const float* an1 = (const float*)d_in[7];
  const float* aw2 = (const float*)d_in[8];
  const float* ab2 = (const float*)d_in[9];
  const float* ag2 = (const float*)d_in[10];
  const float* an2 = (const float*)d_in[11];
  const float* aw3 = (const float*)d_in[12];
  const float* ab3 = (const float*)d_in[13];
  const float* cw1 = (const float*)d_in[14];
  const float* cb1 = (const float*)d_in[15];
  const float* cg1 = (const float*)d_in[16];
  const float* cn1 = (const float*)d_in[17];
  const float* cw2 = (const float*)d_in[18];
  const float* cb2 = (const float*)d_in[19];
  const float* cg2 = (const float*)d_in[20];
  const float* cn2 = (const float*)d_in[21];
  const float* cw3 = (const float*)d_in[22];
  const float* cb3 = (const float*)d_in[23];

  __hip_bfloat16* wbuf = (__hip_bfloat16*)d_ws;
  float* vbuf  = (float*)((char*)d_ws + OFF_V_BYTES);
  float* nvbuf = (float*)((char*)d_ws + OFF_NV_BYTES);
  float* out = (float*)d_out;

  // chunk size adaptive to ws_size (3 bf16 act buffers of C*512 bytes)
  int C = 65536;
  size_t avail = ws_size > (size_t)OFF_H1_BYTES ? ws_size - (size_t)OFF_H1_BYTES : 0;
  while (C > 4096 && (size_t)C * 512 * 3 > avail) C >>= 1;
  __hip_bfloat16* h1a  = (__hip_bfloat16*)((char*)d_ws + OFF_H1_BYTES);
  __hip_bfloat16* h1cs = h1a + (size_t)C * 256;
  __hip_bfloat16* h1cn = h1a + (size_t)2 * C * 256;

  prep_weights<<<(W_ELEMS + 255) / 256, 256, 0, stream>>>(aw1, aw2, aw3, cw1, cw2, cw3, wbuf);

  for (int cb = 0; cb < T_SZ; cb += C) {
    l1_kernel<<<C / 64, 256, 0, stream>>>(
        states, next_states, ab1, ag1, an1, cb1, cg1, cn1,
        wbuf, h1a, h1cs, h1cn, cb);
    actor23_kernel<<<C / 64, 256, 0, stream>>>(
        h1a, ab2, ag2, an2, ab3, wbuf, out, cb);
    critic23_kernel<<<dim3(C / 64, 2), 256, 0, stream>>>(
        h1cs, h1cn, cb2, cg2, cn2, cb3, wbuf, vbuf, nvbuf, cb);
  }
  gae_kernel<<<256, 256, 0, stream>>>(rewards, masks, vbuf, nvbuf, out);
}

// Round 12
// 2089.597 us; speedup vs baseline: 1.7701x; 1.7701x over previous
//
#include <hip/hip_runtime.h>
#include <hip/hip_bf16.h>

// ============================================================================
// PPO agent fused forward (round 12):
//  Law from r1-r11: usable arch VGPRs = budget/2; all designs need 65-128 arch
//  -> locked at 2 waves/SIMD; extra pipeline regs spill (r9), reg-staging
//  spills + conflicts (r10). Fix: DMA staging via global_load_lds -- zero
//  registers, zero VALU.
//   - prep_weights writes ws in FRAGMENT-MAJOR order: chunk p (32 out-cols),
//     16 blocks of 1KB, block (rh*NK+ks), lane l's 16B = the exact B-frag
//     lane l consumes. Linear LDS image == read order: ds_read_b128 with all
//     lanes at consecutive 16B -> conflict-free, base+offset addressing.
//   - per chunk: issue DMA for chunk p+1 -> compute chunk p -> __syncthreads
//     (vmcnt drain lands one full chunk-compute after issue = latency hidden).
//   - weights staged once per block: B global traffic /4 vs r7.
//  Same numerics as r7/r8 (absmax 0.125-0.25 < 0.34).
// ============================================================================

#define T_SZ 524288
#define GL 0.9405f   // GAMMA*LAM

typedef __attribute__((ext_vector_type(8))) short bf16x8;   // 8 bf16 (4 VGPRs)
typedef __attribute__((ext_vector_type(4))) float f32x4;
typedef __attribute__((address_space(1))) const void* gas_t;
typedef __attribute__((address_space(3))) void* las_t;

// ws layout (bf16 elements); weights in fragment-major chunk layout
#define OFF_AW1T 0        // 256x64
#define OFF_AW2T 16384    // 256x256
#define OFF_AW3T 81920    // 32x256 (rows >=18 zero)
#define OFF_CW1T 90112    // 256x64
#define OFF_CW2T 106496   // 256x256
#define OFF_CW3T 172032   // 16x256 (rows >=1 zero)
#define W_ELEMS  176128
#define OFF_DELTAS_BYTES 352256

// k = p*32 + h*16 + w -> pos = p*32 + w*2 + h (applied to A and B alike)
__device__ __forceinline__ int perm_k(int k) {
  return (k & ~31) | ((k & 15) << 1) | ((k >> 4) & 1);
}

__device__ __forceinline__ unsigned pack2(float a, float b) {
  union { __hip_bfloat16 h; unsigned short u; } ua, ub;
  ua.h = __float2bfloat16(a); ub.h = __float2bfloat16(b);
  return (unsigned)ua.u | ((unsigned)ub.u << 16);
}

__device__ __forceinline__ void unpack2(unsigned u, float& a, float& b) {
  union { unsigned u; float f; } x, y;
  x.u = u << 16; y.u = u & 0xFFFF0000u;
  a = x.f; b = y.f;
}

// per-wave ACT stash accessor (stride 512B, 16B-granular XOR on row&7)
__device__ __forceinline__ void* act_at(void* base, int row, int colByte) {
  return (char*)base + row * 512 + (colByte ^ ((row & 7) << 4));
}

// ---------------------------------------------------------------------------
// DMA stage: BYTES (multiple of 4096) from global src to LDS dst, 4 waves.
// Wave w covers 1KB segments s = r*4 + w; HW writes dst+s*1024+lane*16.
template<int BYTES>
__device__ __forceinline__ void stage(const char* __restrict__ src,
                                      char* dst, int wave, int lane) {
#pragma unroll
  for (int r = 0; r < BYTES / 4096; ++r) {
    const int s = r * 4 + wave;
    __builtin_amdgcn_global_load_lds((gas_t)(src + s * 1024 + lane * 16),
                                     (las_t)(dst + s * 1024), 16, 0, 0);
  }
}

// ---------------------------------------------------------------------------
// X tile (16 rows x 64 fp32) -> 2 k-permuted bf16x8 frags per lane.
__device__ __forceinline__ void load_x_frags(const float* __restrict__ src,
                                             int c, int q, bf16x8* xf) {
  const float* rp = src + (size_t)c * 64;
#pragma unroll
  for (int ks = 0; ks < 2; ++ks) {
    float4 a = *(const float4*)(rp + ks * 32 + 4 * q);
    float4 b = *(const float4*)(rp + ks * 32 + 4 * q + 16);
    unsigned u[4];
    u[0] = pack2(a.x, b.x); u[1] = pack2(a.y, b.y);
    u[2] = pack2(a.z, b.z); u[3] = pack2(a.w, b.w);
    xf[ks] = *(bf16x8*)u;
  }
}

// shared LN tail: reduce s/ss, broadcast row-c stats -> (mc, rc)
__device__ __forceinline__ void ln_stats(float* s, float* ss, int c,
                                         float& mc, float& rc) {
#pragma unroll
  for (int m = 1; m < 16; m <<= 1) {
#pragma unroll
    for (int r = 0; r < 4; ++r) {
      s[r]  += __shfl_xor(s[r],  m, 64);
      ss[r] += __shfl_xor(ss[r], m, 64);
    }
  }
  float mean[4], rs[4];
#pragma unroll
  for (int r = 0; r < 4; ++r) {
    mean[r] = s[r] * (1.f / 256.f);
    float var = ss[r] * (1.f / 256.f) - mean[r] * mean[r];
    rs[r] = rsqrtf(var + 1e-5f);
  }
  const int srcLane = ((c >> 2) << 4) + c;
  float mb[4], rb[4];
#pragma unroll
  for (int r = 0; r < 4; ++r) {
    mb[r] = __shfl(mean[r], srcLane, 64);
    rb[r] = __shfl(rs[r],   srcLane, 64);
  }
  const float m01 = (c & 1) ? mb[1] : mb[0], m23 = (c & 1) ? mb[3] : mb[2];
  const float r01 = (c & 1) ? rb[1] : rb[0], r23 = (c & 1) ? rb[3] : rb[2];
  mc = (c & 2) ? m23 : m01;
  rc = (c & 2) ? r23 : r01;
}

// post-stats: build next-layer frags from pre-LN ACT (normalize+ReLU in regs)
__device__ __forceinline__ void build_frags(void* ACT,
    const float* __restrict__ gam, const float* __restrict__ bet,
    float mc, float rc, int c, int q, bf16x8* of) {
#pragma unroll
  for (int ks = 0; ks < 8; ++ks) {
    uint4 dv = *(const uint4*)act_at(ACT, c, ks * 64 + q * 16);
    unsigned w[4];
    const unsigned* dp = (const unsigned*)&dv;
#pragma unroll
    for (int i = 0; i < 4; ++i) {
      const int n0 = ks * 32 + q * 4 + i;
      float v0, v1;
      unpack2(dp[i], v0, v1);
      float w0 = fmaxf((v0 - mc) * rc * gam[n0]      + bet[n0],      0.f);
      float w1 = fmaxf((v1 - mc) * rc * gam[n0 + 16] + bet[n0 + 16], 0.f);
      w[i] = pack2(w0, w1);
    }
    of[ks] = *(bf16x8*)w;
  }
}

// ---------------------------------------------------------------------------
// K=64 layer: stage whole 32KB W, 1 barrier, 8 chunk computes, LN, frags out.
__device__ __forceinline__ void layer64(const bf16x8* xf,
    const char* __restrict__ Wsrc,
    const float* __restrict__ bias, const float* __restrict__ gam,
    const float* __restrict__ bet, void* ACT, char* B,
    int c, int q, int wave, int lane, bf16x8* of) {
  __syncthreads();                       // prior readers of B are done
  stage<32768>(Wsrc, B, wave, lane);
  __syncthreads();                       // W resident
  float s[4] = {0, 0, 0, 0}, ss[4] = {0, 0, 0, 0};
#pragma unroll
  for (int p = 0; p < 8; ++p) {
    const char* LB = B + p * 4096;
    f32x4 a0 = {0.f, 0.f, 0.f, 0.f}, a1 = {0.f, 0.f, 0.f, 0.f};
#pragma unroll
    for (int ks = 0; ks < 2; ++ks) {
      bf16x8 b0 = *(const bf16x8*)(LB + ks * 1024 + lane * 16);
      bf16x8 b1 = *(const bf16x8*)(LB + (2 + ks) * 1024 + lane * 16);
      a0 = __builtin_amdgcn_mfma_f32_16x16x32_bf16(xf[ks], b0, a0, 0, 0, 0);
      a1 = __builtin_amdgcn_mfma_f32_16x16x32_bf16(xf[ks], b1, a1, 0, 0, 0);
    }
    const float bb0 = bias[32 * p + c], bb1 = bias[32 * p + 16 + c];
#pragma unroll
    for (int r = 0; r < 4; ++r) {
      float v0 = a0[r] + bb0, v1 = a1[r] + bb1;
      s[r] += v0 + v1;
      ss[r] += v0 * v0 + v1 * v1;
      *(unsigned*)act_at(ACT, q * 4 + r, p * 64 + c * 4) = pack2(v0, v1);
    }
  }
  float mc, rc;
  ln_stats(s, ss, c, mc, rc);
  build_frags(ACT, gam, bet, mc, rc, c, q, of);
}

// ---------------------------------------------------------------------------
// K=256 layer: double-buffered 16KB chunks; DMA for p+1 issued before
// compute of p; __syncthreads per chunk (vmcnt drain = one compute later).
__device__ __forceinline__ void layer256(const bf16x8* af,
    const char* __restrict__ Wsrc,
    const float* __restrict__ bias, const float* __restrict__ gam,
    const float* __restrict__ bet, void* ACT, char* B,
    int c, int q, int wave, int lane, bf16x8* of) {
  __syncthreads();                       // prior readers of B are done
  stage<16384>(Wsrc, B, wave, lane);     // chunk 0 -> low half
  __syncthreads();
  float s[4] = {0, 0, 0, 0}, ss[4] = {0, 0, 0, 0};
#pragma unroll
  for (int p = 0; p < 8; ++p) {
    const char* LB = B + (p & 1) * 16384;
    if (p < 7)
      stage<16384>(Wsrc + (size_t)(p + 1) * 16384,
                   B + ((p + 1) & 1) * 16384, wave, lane);
    f32x4 a0 = {0.f, 0.f, 0.f, 0.f}, a1 = {0.f, 0.f, 0.f, 0.f};
#pragma unroll
    for (int ks = 0; ks < 8; ++ks) {
      bf16x8 b0 = *(const bf16x8*)(LB + ks * 1024 + lane * 16);
      bf16x8 b1 = *(const bf16x8*)(LB + (8 + ks) * 1024 + lane * 16);
      a0 = __builtin_amdgcn_mfma_f32_16x16x32_bf16(af[ks], b0, a0, 0, 0, 0);
      a1 = __builtin_amdgcn_mfma_f32_16x16x32_bf16(af[ks], b1, a1, 0, 0, 0);
    }
    const float bb0 = bias[32 * p + c], bb1 = bias[32 * p + 16 + c];
#pragma unroll
    for (int r = 0; r < 4; ++r) {
      float v0 = a0[r] + bb0, v1 = a1[r] + bb1;
      s[r] += v0 + v1;
      ss[r] += v0 * v0 + v1 * v1;
      *(unsigned*)act_at(ACT, q * 4 + r, p * 64 + c * 4) = pack2(v0, v1);
    }
    if (p < 7) __syncthreads();          // chunk p+1 resident; p's buf free
  }
  float mc, rc;
  ln_stats(s, ss, c, mc, rc);
  build_frags(ACT, gam, bet, mc, rc, c, q, of);
}

// small final GEMM: NT column-tiles of 16, K=256, whole W staged once
template<int NT>
__device__ __forceinline__ void run_small(const bf16x8* af,
    const char* __restrict__ Wsrc, char* B,
    int c, int q, int wave, int lane, f32x4* acc) {
  __syncthreads();
  stage<NT * 8192>(Wsrc, B, wave, lane);
  __syncthreads();
#pragma unroll
  for (int nt = 0; nt < NT; ++nt) acc[nt] = (f32x4){0.f, 0.f, 0.f, 0.f};
#pragma unroll
  for (int ks = 0; ks < 8; ++ks) {
#pragma unroll
    for (int nt = 0; nt < NT; ++nt) {
      bf16x8 b = *(const bf16x8*)(B + (nt * 8 + ks) * 1024 + lane * 16);
      acc[nt] = __builtin_amdgcn_mfma_f32_16x16x32_bf16(af[ks], b, acc[nt], 0, 0, 0);
    }
  }
}

__device__ __forceinline__ void softmax_write(f32x4* acc3,
    const float* __restrict__ ab3, float* __restrict__ out,
    int grow0, int c, int q) {
  float b0 = ab3[c];
  float b1 = (c < 2) ? ab3[16 + c] : 0.f;
#pragma unroll
  for (int r = 0; r < 4; ++r) {
    float x0 = acc3[0][r] + b0;
    float x1 = (c < 2) ? (acc3[1][r] + b1) : -1e30f;
    float mx = fmaxf(x0, x1);
#pragma unroll
    for (int m = 1; m < 16; m <<= 1) mx = fmaxf(mx, __shfl_xor(mx, m, 64));
    float e0 = __expf(x0 - mx);
    float e1 = (c < 2) ? __expf(x1 - mx) : 0.f;
    float sm = e0 + e1;
#pragma unroll
    for (int m = 1; m < 16; m <<= 1) sm += __shfl_xor(sm, m, 64);
    float inv = 1.f / sm;
    int gr = grow0 + q * 4 + r;
    out[(size_t)gr * 20 + c] = e0 * inv;
    if (c < 2) out[(size_t)gr * 20 + 16 + c] = e1 * inv;
  }
}

// ---------------------------------------------------------------------------
// prep: fragment-major chunk layout. For weight (n,k) of a [N][K] matrix:
// chunk p=n>>5, rh=(n>>4)&1, c=n&15; kp=perm_k(k), ks=kp>>5, q=(kp&31)>>3,
// e=kp&7 -> elem = mo + p*(32K) + (rh*(K/32)+ks)*512 + (q*16+c)*8 + e.
__device__ __forceinline__ int frag_idx(int mo, int K, int n, int k) {
  const int kp = perm_k(k);
  const int p = n >> 5, rh = (n >> 4) & 1, cc = n & 15;
  const int ks = kp >> 5, w = kp & 31, qq = w >> 3, e = w & 7;
  return mo + p * (K * 32) + (rh * (K / 32) + ks) * 512 + (qq * 16 + cc) * 8 + e;
}

__global__ void prep_weights(const float* __restrict__ aw1, const float* __restrict__ aw2,
                             const float* __restrict__ aw3, const float* __restrict__ cw1,
                             const float* __restrict__ cw2, const float* __restrict__ cw3,
                             __hip_bfloat16* __restrict__ wb) {
  int i = blockIdx.x * 256 + threadIdx.x;
  if (i >= W_ELEMS) return;
  float v; int dst;
  if (i < OFF_AW2T)      { int j = i;            int n = j >> 6, k = j & 63;  v = aw1[k * 256 + n];                 dst = frag_idx(OFF_AW1T, 64,  n, k); }
  else if (i < OFF_AW3T) { int j = i - OFF_AW2T; int n = j >> 8, k = j & 255; v = aw2[k * 256 + n];                 dst = frag_idx(OFF_AW2T, 256, n, k); }
  else if (i < OFF_CW1T) { int j = i - OFF_AW3T; int n = j >> 8, k = j & 255; v = (n < 18) ? aw3[k * 18 + n] : 0.f; dst = frag_idx(OFF_AW3T, 256, n, k); }
  else if (i < OFF_CW2T) { int j = i - OFF_CW1T; int n = j >> 6, k = j & 63;  v = cw1[k * 256 + n];                 dst = frag_idx(OFF_CW1T, 64,  n, k); }
  else if (i < OFF_CW3T) { int j = i - OFF_CW2T; int n = j >> 8, k = j & 255; v = cw2[k * 256 + n];                 dst = frag_idx(OFF_CW2T, 256, n, k); }
  else                   { int j = i - OFF_CW3T; int n = j >> 8, k = j & 255; v = (n == 0) ? cw3[k] : 0.f;          dst = frag_idx(OFF_CW3T, 256, n, k); }
  wb[dst] = __float2bfloat16(v);
}

// ---------------------------------------------------------------------------
__global__ __launch_bounds__(256, 2) void mlp_kernel(
    const float* __restrict__ states, const float* __restrict__ next_states,
    const float* __restrict__ rewards, const float* __restrict__ masks,
    const float* __restrict__ ab1, const float* __restrict__ ag1, const float* __restrict__ an1,
    const float* __restrict__ ab2, const float* __restrict__ ag2, const float* __restrict__ an2,
    const float* __restrict__ ab3,
    const float* __restrict__ cb1, const float* __restrict__ cg1, const float* __restrict__ cn1,
    const float* __restrict__ cb2, const float* __restrict__ cg2, const float* __restrict__ cn2,
    const float* __restrict__ cb3,
    const __hip_bfloat16* __restrict__ wbuf,
    float* __restrict__ deltas, float* __restrict__ out) {
  __shared__ char Bbuf[32768];        // staged weights (dbuf halves for K=256)
  __shared__ char ACTb[4][8192];      // per-wave pre-LN stash
  const int tid = threadIdx.x;
  const int wave = tid >> 6, lane = tid & 63;
  const int c = lane & 15, q = lane >> 4;
  char* B = Bbuf;
  void* ACT = (void*)ACTb[wave];
  const char* W = (const char*)wbuf;
  const int base = blockIdx.x * 64 + wave * 16;   // 16 timesteps per wave

  bf16x8 xf[2], af[8];

  // ---- X(states) -> regs, shared by actor-L1 and critic-L1 ----
  load_x_frags(states + (size_t)base * 64, c, q, xf);

  // ---- ACTOR(states) ----
  layer64(xf, W + OFF_AW1T * 2, ab1, ag1, an1, ACT, B, c, q, wave, lane, af);
  layer256(af, W + OFF_AW2T * 2, ab2, ag2, an2, ACT, B, c, q, wave, lane, af);
  {
    f32x4 p3[2];
    run_small<2>(af, W + OFF_AW3T * 2, B, c, q, wave, lane, p3);
    softmax_write(p3, ab3, out, base, c, q);
  }

  // ---- CRITIC(states) ---- (xf still in regs)
  layer64(xf, W + OFF_CW1T * 2, cb1, cg1, cn1, ACT, B, c, q, wave, lane, af);
  layer256(af, W + OFF_CW2T * 2, cb2, cg2, cn2, ACT, B, c, q, wave, lane, af);
  float vst[4];
  {
    f32x4 v[1];
    run_small<1>(af, W + OFF_CW3T * 2, B, c, q, wave, lane, v);
    const float b3 = cb3[0];
#pragma unroll
    for (int r = 0; r < 4; ++r) vst[r] = v[0][r] + b3;
  }

  // ---- CRITIC(next_states) ----
  load_x_frags(next_states + (size_t)base * 64, c, q, xf);
  layer64(xf, W + OFF_CW1T * 2, cb1, cg1, cn1, ACT, B, c, q, wave, lane, af);
  layer256(af, W + OFF_CW2T * 2, cb2, cg2, cn2, ACT, B, c, q, wave, lane, af);
  {
    f32x4 v[1];
    run_small<1>(af, W + OFF_CW3T * 2, B, c, q, wave, lane, v);
    const float b3 = cb3[0];
    if (c == 0) {
#pragma unroll
      for (int r = 0; r < 4; ++r) {
        const int gr = base + q * 4 + r;
        const float nv = v[0][r] + b3;
        out[(size_t)gr * 20 + 19] = vst[r];   // stash value; gae -> return
        deltas[gr] = rewards[gr] + 0.99f * nv * masks[gr] - vst[r];
      }
    }
  }
}

// ---------------------------------------------------------------------------
// GAE, wave-parallel: each wave owns a 512-elem chunk + 512-elem lookahead.
// Truncation: GL^512 ~ 2e-14. value stashed at out[:,19] -> returns.
__global__ __launch_bounds__(256) void gae_kernel(
    const float* __restrict__ deltas, const float* __restrict__ masks,
    float* __restrict__ out) {
  const int w = (blockIdx.x * blockDim.x + threadIdx.x) >> 6;  // 0..1023
  const int lane = threadIdx.x & 63;
  const int idx0 = w * 512 + lane * 16;

  float d[16], cf[16];
  if (idx0 < T_SZ) {
#pragma unroll
    for (int i = 0; i < 4; ++i) {
      *(float4*)(d + i * 4)  = *(const float4*)(deltas + idx0 + i * 4);
      *(float4*)(cf + i * 4) = *(const float4*)(masks + idx0 + i * 4);
    }
#pragma unroll
    for (int i = 0; i < 16; ++i) cf[i] *= GL;
  } else {
#pragma unroll
    for (int i = 0; i < 16; ++i) { d[i] = 0.f; cf[i] = 0.f; }
  }

  float A = 0.f, P = 1.f;
#pragma unroll
  for (int i = 15; i >= 0; --i) { A = d[i] + cf[i] * A; P *= cf[i]; }

  float As = A, Ps = P;
#pragma unroll
  for (int st = 1; st < 64; st <<= 1) {
    float An = __shfl_down(As, st, 64);
    float Pn = __shfl_down(Ps, st, 64);
    if (lane + st < 64) { As = As + Ps * An; Ps = Ps * Pn; }
  }
  float G = __shfl_down(As, 1, 64);
  if (lane == 63) G = 0.f;

  if (lane < 32) {
    float g = G;
#pragma unroll
    for (int i = 15; i >= 0; --i) {
      g = d[i] + cf[i] * g;
      const size_t j = (size_t)(idx0 + i);
      float val = out[j * 20 + 19];
      out[j * 20 + 18] = g;
      out[j * 20 + 19] = g + val;
    }
  }
}

// ---------------------------------------------------------------------------
extern "C" void kernel_launch(void* const* d_in, const int* in_sizes, int n_in,
                              void* d_out, int out_size, void* d_ws, size_t ws_size,
                              hipStream_t stream) {
  const float* states      = (const float*)d_in[0];
  const float* next_states = (const float*)d_in[1];
  const float* rewards     = (const float*)d_in[2];
  const float* masks       = (const float*)d_in[3];
  const float* aw1 = (const float*)d_in[4];
  const float* ab1 = (const float*)d_in[5];
  const float* ag1 = (const float*)d_in[6];
  const float* an1 = (const float*)d_in[7];
  const float* aw2 = (const float*)d_in[8];
  const float* ab2 = (const float*)d_in[9];
  const float* ag2 = (const float*)d_in[10];
  const float* an2 = (const float*)d_in[11];
  const float* aw3 = (const float*)d_in[12];
  const float* ab3 = (const float*)d_in[13];
  const float* cw1 = (const float*)d_in[14];
  const float* cb1 = (const float*)d_in[15];
  const float* cg1 = (const float*)d_in[16];
  const float* cn1 = (const float*)d_in[17];
  const float* cw2 = (const float*)d_in[18];
  const float* cb2 = (const float*)d_in[19];
  const float* cg2 = (const float*)d_in[20];
  const float* cn2 = (const float*)d_in[21];
  const float* cw3 = (const float*)d_in[22];
  const float* cb3 = (const float*)d_in[23];

  __hip_bfloat16* wbuf = (__hip_bfloat16*)d_ws;
  float* deltas = (float*)((char*)d_ws + OFF_DELTAS_BYTES);
  float* out = (float*)d_out;

  prep_weights<<<(W_ELEMS + 255) / 256, 256, 0, stream>>>(aw1, aw2, aw3, cw1, cw2, cw3, wbuf);
  mlp_kernel<<<T_SZ / 64, 256, 0, stream>>>(
      states, next_states, rewards, masks,
      ab1, ag1, an1, ab2, ag2, an2, ab3,
      cb1, cg1, cn1, cb2, cg2, cn2, cb3,
      wbuf, deltas, out);
  gae_kernel<<<256, 256, 0, stream>>>(deltas, masks, out);
}